// Round 5
// baseline (537.096 us; speedup 1.0000x reference)
//
#include <hip/hip_runtime.h>

// ---------------------------------------------------------------------------
// out = 0.5*F + 0.5*softmax((F Wq^T)(M Wk^T)^T) M ;  N=M=8192, H=512, fp32.
// R5: 64-key K tiles via global_load_lds (inline pack), V B-frags direct from
// global (packed, coalesced), trigger softmax, 4 dispatches total.
// ---------------------------------------------------------------------------

typedef _Float16 half8 __attribute__((ext_vector_type(8)));
typedef float floatx4 __attribute__((ext_vector_type(4)));

#define MFMA16(a, b, c) __builtin_amdgcn_mfma_f32_16x16x32_f16((a), (b), (c), 0, 0, 0)

static constexpr int H = 512;
static constexpr int NROWS = 8192;

__device__ __forceinline__ void dma16(half8* lds_dst, const void* g_src) {
    __builtin_amdgcn_global_load_lds(
        (const __attribute__((address_space(1))) unsigned int*)g_src,
        (__attribute__((address_space(3))) unsigned int*)lds_dst,
        16, 0, 0);
}

// ---------------------------------------------------------------------------
// K0: fused  (blocks 0..2047: pack V to B-frag order; 2048..4095: cast W).
// V[key=kb*32+g*8+j][d=db*16+c] -> vp8[kb*2048 + db*64 + g*16+c][j]
// ---------------------------------------------------------------------------
__global__ void packcast_kernel(const float* __restrict__ mem, half8* __restrict__ vp,
                                const float* __restrict__ wq, const float* __restrict__ wk,
                                _Float16* __restrict__ wq16, _Float16* __restrict__ wk16) {
    int b = blockIdx.x;
    if (b < 2048) {
        int cid = b * 256 + threadIdx.x;
        int kb  = cid >> 11;
        int rem = cid & 2047;
        int db  = rem >> 6;
        int gc  = rem & 63;
        int g   = gc >> 4, c = gc & 15;
        const float* src = mem + (size_t)(kb * 32 + g * 8) * H + db * 16 + c;
        half8 v;
#pragma unroll
        for (int j = 0; j < 8; ++j) v[j] = (_Float16)src[(size_t)j * H];
        vp[cid] = v;
    } else {
        int i = (b - 2048) * 256 + threadIdx.x;
        if (i < 262144) wq16[i] = (_Float16)wq[i];
        else            wk16[i - 262144] = (_Float16)wk[i - 262144];
    }
}

// ---------------------------------------------------------------------------
// K1: both projections (z=0: q = F@Wq^T+bq ; z=1: k = M@Wk^T+bk), fp16 out.
// ---------------------------------------------------------------------------
__global__ __launch_bounds__(256, 4)
void proj_kernel(const float* __restrict__ X0, const _Float16* __restrict__ W0,
                 const float* __restrict__ b0, _Float16* __restrict__ out0,
                 const float* __restrict__ X1, const _Float16* __restrict__ W1,
                 const float* __restrict__ b1, _Float16* __restrict__ out1) {
    const float* X = blockIdx.z ? X1 : X0;
    const _Float16* W16 = blockIdx.z ? W1 : W0;
    const float* bias = blockIdx.z ? b1 : b0;
    _Float16* out = blockIdx.z ? out1 : out0;

    const int lane = threadIdx.x & 63;
    const int wave = threadIdx.x >> 6;
    const int row0 = blockIdx.x * 64 + wave * 16;
    const int col0 = blockIdx.y * 64;
    const int lr = lane & 15, lq = lane >> 4;

    floatx4 acc[4];
#pragma unroll
    for (int nt = 0; nt < 4; ++nt) { acc[nt][0] = 0.f; acc[nt][1] = 0.f; acc[nt][2] = 0.f; acc[nt][3] = 0.f; }

    const float* arow = X + (size_t)(row0 + lr) * H + lq * 8;
    const half8* wbase = (const half8*)W16;

#pragma unroll
    for (int kk = 0; kk < 16; ++kk) {
        floatx4 a0 = *(const floatx4*)(arow + kk * 32);
        floatx4 a1 = *(const floatx4*)(arow + kk * 32 + 4);
        half8 af;
        af[0] = (_Float16)a0[0]; af[1] = (_Float16)a0[1];
        af[2] = (_Float16)a0[2]; af[3] = (_Float16)a0[3];
        af[4] = (_Float16)a1[0]; af[5] = (_Float16)a1[1];
        af[6] = (_Float16)a1[2]; af[7] = (_Float16)a1[3];
#pragma unroll
        for (int nt = 0; nt < 4; ++nt) {
            half8 bf = wbase[(size_t)(col0 + nt * 16 + lr) * 64 + kk * 4 + lq];
            acc[nt] = MFMA16(af, bf, acc[nt]);
        }
    }
#pragma unroll
    for (int nt = 0; nt < 4; ++nt) {
        int col = col0 + nt * 16 + lr;
        float bv = bias[col];
#pragma unroll
        for (int r = 0; r < 4; ++r) {
            int row = row0 + lq * 4 + r;
            out[(size_t)row * H + col] = (_Float16)(acc[nt][r] + bv);
        }
    }
}

// ---------------------------------------------------------------------------
// K2: flash attention. blockIdx.x = rbk*4+slice; 64 q-rows, slice owns 2048
// keys as 32 tiles of 64. QK: wave = 16-row stripe, K tile from LDS (DMA'd
// with inline B-frag packing). PV: wave = 128-wide d-slice, V B-frags direct
// from global (coalesced). Trigger softmax (m bumps only when tile max
// exceeds m+10; e^10 < fp16 max so P stays representable).
// ---------------------------------------------------------------------------
__global__ __launch_bounds__(256, 2)
void flash_kernel(const _Float16* __restrict__ q16, const _Float16* __restrict__ k16,
                  const half8* __restrict__ vp, _Float16* __restrict__ opart,
                  float* __restrict__ mpart, float* __restrict__ lpart) {
    __shared__ half8 klds[4096];          // 64 KB: K tile (64 keys), B-frag order
    __shared__ _Float16 plds[64 * 72];    // 64 rows x 64 keys, stride 72
    __shared__ float alds[64];
    __shared__ float llds[64];
    __shared__ int flagld;

    const int tid = threadIdx.x;
    const int lane = tid & 63;
    const int wave = tid >> 6;
    const int rbk = blockIdx.x >> 2;
    const int slice = blockIdx.x & 3;
    const int row0 = rbk * 64;
    const int lr = lane & 15, lq = lane >> 4;

    // K-DMA addressing: LDS dst d = tid+i*256 -> [c][kk][g][cc];
    // src = key (c*16+cc) row * 512 + kk*32 + g*8 halves within 64-key tile.
    int koff[16];
#pragma unroll
    for (int i = 0; i < 16; ++i) {
        int d = tid + i * 256;
        int c = d >> 10, kk = (d >> 6) & 15, g = (d >> 4) & 3, cc = d & 15;
        koff[i] = (c * 16 + cc) * 512 + kk * 32 + g * 8;
    }

    // Q stripe: lane holds q16[row0+wave*16+lr][kk*32+lq*8 ..]
    const half8* qrow = (const half8*)(q16 + (size_t)(row0 + wave * 16 + lr) * H);
    half8 qf[16];
#pragma unroll
    for (int kk = 0; kk < 16; ++kk) qf[kk] = qrow[kk * 4 + lq];

    floatx4 o[4][8];
#pragma unroll
    for (int rb = 0; rb < 4; ++rb)
#pragma unroll
        for (int f = 0; f < 8; ++f) { o[rb][f][0] = 0.f; o[rb][f][1] = 0.f; o[rb][f][2] = 0.f; o[rb][f][3] = 0.f; }
    float m[4], l[4];
#pragma unroll
    for (int r = 0; r < 4; ++r) { m[r] = -1e30f; l[r] = 0.f; }

    for (int kt = slice * 32; kt < slice * 32 + 32; ++kt) {
        __syncthreads();                                   // B1: prev tile consumed
        if (tid == 0) flagld = 0;

        const _Float16* ksrc = k16 + (size_t)kt * 32768;   // 64 rows x 512
#pragma unroll
        for (int i = 0; i < 16; ++i) dma16(&klds[tid + i * 256], ksrc + koff[i]);

        __syncthreads();                                   // B2: DMA drained

        // ---- QK^T: S[16 x 64] per wave, K frags from LDS ----
        floatx4 s[4];
#pragma unroll
        for (int c = 0; c < 4; ++c) { s[c][0] = 0.f; s[c][1] = 0.f; s[c][2] = 0.f; s[c][3] = 0.f; }
#pragma unroll
        for (int kk = 0; kk < 16; ++kk) {
#pragma unroll
            for (int c = 0; c < 4; ++c)
                s[c] = MFMA16(qf[kk], klds[c * 1024 + kk * 64 + lane], s[c]);
        }

        // ---- trigger check ----
        float tm[4]; int trig = 0;
#pragma unroll
        for (int r = 0; r < 4; ++r) {
            tm[r] = fmaxf(fmaxf(s[0][r], s[1][r]), fmaxf(s[2][r], s[3][r]));
            trig |= (tm[r] > m[r] + 10.f) ? 1 : 0;
        }
        if (__any(trig)) {
            float al[4];
#pragma unroll
            for (int r = 0; r < 4; ++r) {
                float mx = tm[r];
                mx = fmaxf(mx, __shfl_xor(mx, 1));
                mx = fmaxf(mx, __shfl_xor(mx, 2));
                mx = fmaxf(mx, __shfl_xor(mx, 4));
                mx = fmaxf(mx, __shfl_xor(mx, 8));
                float mn = (mx > m[r] + 10.f) ? mx : m[r];
                al[r] = __expf(m[r] - mn);
                m[r] = mn;
                l[r] *= al[r];
            }
            if (lr == 0) {
#pragma unroll
                for (int r = 0; r < 4; ++r) alds[wave * 16 + lq * 4 + r] = al[r];
            }
            if (lane == 0) flagld = 1;
        } else {
            if (lr == 0) {
#pragma unroll
                for (int r = 0; r < 4; ++r) alds[wave * 16 + lq * 4 + r] = 1.0f;
            }
        }

        // ---- exp, lane-local l, P -> LDS ----
#pragma unroll
        for (int r = 0; r < 4; ++r) {
            int prow = (wave * 16 + lq * 4 + r) * 72;
#pragma unroll
            for (int c = 0; c < 4; ++c) {
                float p = __expf(s[c][r] - m[r]);
                l[r] += p;
                plds[prow + c * 16 + lr] = (_Float16)p;
            }
        }

        __syncthreads();                                   // B3: P + alds ready

        if (flagld) {
#pragma unroll
            for (int rb = 0; rb < 4; ++rb)
#pragma unroll
                for (int rr = 0; rr < 4; ++rr) {
                    float a = alds[rb * 16 + lq * 4 + rr];
#pragma unroll
                    for (int f = 0; f < 8; ++f) o[rb][f][rr] *= a;
                }
        }

        // ---- PV: wave owns d-slice [wave*128, +128); V frags from global ----
        half8 pf0[4], pf1[4];
#pragma unroll
        for (int rb = 0; rb < 4; ++rb) {
            pf0[rb] = *(const half8*)&plds[(rb * 16 + lr) * 72 + lq * 8];
            pf1[rb] = *(const half8*)&plds[(rb * 16 + lr) * 72 + 32 + lq * 8];
        }
        const half8* vb0 = vp + (size_t)(2 * kt) * 2048 + wave * 512;      // keys 0..31
        const half8* vb1 = vb0 + 2048;                                     // keys 32..63
#pragma unroll
        for (int f = 0; f < 8; ++f) {
            half8 vf0 = vb0[f * 64 + lane];
            half8 vf1 = vb1[f * 64 + lane];
#pragma unroll
            for (int rb = 0; rb < 4; ++rb) {
                o[rb][f] = MFMA16(pf0[rb], vf0, o[rb][f]);
                o[rb][f] = MFMA16(pf1[rb], vf1, o[rb][f]);
            }
        }
    }

    // ---- final l reduction over the 16 lr lanes ----
#pragma unroll
    for (int r = 0; r < 4; ++r) {
        float lv = l[r];
        lv += __shfl_xor(lv, 1); lv += __shfl_xor(lv, 2);
        lv += __shfl_xor(lv, 4); lv += __shfl_xor(lv, 8);
        l[r] = lv;
    }
    if (lr == 0) {
#pragma unroll
        for (int r = 0; r < 4; ++r) {
            int row = wave * 16 + lq * 4 + r;
            llds[row] = l[r];
            mpart[slice * NROWS + row0 + row] = m[r];
            lpart[slice * NROWS + row0 + row] = l[r];
        }
    }
    __syncthreads();

    // ---- normalized O store (fp16) ----
    _Float16* ob = opart + (size_t)slice * NROWS * H;
#pragma unroll
    for (int rb = 0; rb < 4; ++rb) {
#pragma unroll
        for (int rr = 0; rr < 4; ++rr) {
            float linv = 1.0f / llds[rb * 16 + lq * 4 + rr];
            size_t row = row0 + rb * 16 + lq * 4 + rr;
#pragma unroll
            for (int f = 0; f < 8; ++f)
                ob[row * H + wave * 128 + f * 16 + lr] = (_Float16)(o[rb][f][rr] * linv);
        }
    }
}

// ---------------------------------------------------------------------------
// K3: merge normalized slice partials, weight = e^{m_s - max} * l_s.
// ---------------------------------------------------------------------------
__global__ void merge_kernel(const _Float16* __restrict__ opart, const float* __restrict__ mpart,
                             const float* __restrict__ lpart, const float* __restrict__ F,
                             float* __restrict__ out) {
    int idx = blockIdx.x * 256 + threadIdx.x;
    int row = idx >> 9;
    float m0 = mpart[row], m1 = mpart[NROWS + row], m2 = mpart[2 * NROWS + row], m3 = mpart[3 * NROWS + row];
    float ms = fmaxf(fmaxf(m0, m1), fmaxf(m2, m3));
    float w0 = __expf(m0 - ms) * lpart[row];
    float w1 = __expf(m1 - ms) * lpart[NROWS + row];
    float w2 = __expf(m2 - ms) * lpart[2 * NROWS + row];
    float w3 = __expf(m3 - ms) * lpart[3 * NROWS + row];
    float denom = w0 + w1 + w2 + w3;
    size_t stride = (size_t)NROWS * H;
    float num = w0 * (float)opart[idx] + w1 * (float)opart[stride + idx] +
                w2 * (float)opart[2 * stride + idx] + w3 * (float)opart[3 * stride + idx];
    out[idx] = 0.5f * F[idx] + 0.5f * (num / denom);
}

// ---------------------------------------------------------------------------
// Workspace (~59 MB):
//   [ 0M,  8M) q16   [ 8M, 16M) k16   [16M, 24M) vp   [24M, 56M) opart fp16
//   [56M,+128K) mpart  [+128K,+128K) lpart  [57M,+1M) wq16/wk16
// ---------------------------------------------------------------------------
extern "C" void kernel_launch(void* const* d_in, const int* in_sizes, int n_in,
                              void* d_out, int out_size, void* d_ws, size_t ws_size,
                              hipStream_t stream) {
    const float* F   = (const float*)d_in[0];
    const float* Mem = (const float*)d_in[1];
    const float* Wq  = (const float*)d_in[2];
    const float* bq  = (const float*)d_in[3];
    const float* Wk  = (const float*)d_in[4];
    const float* bk  = (const float*)d_in[5];
    float* out = (float*)d_out;

    char* ws = (char*)d_ws;
    _Float16* q16   = (_Float16*)(ws);
    _Float16* k16   = (_Float16*)(ws + (8ull << 20));
    half8*    vp    = (half8*)(ws + (16ull << 20));
    _Float16* opart = (_Float16*)(ws + (24ull << 20));
    float*    mpart = (float*)(ws + (56ull << 20));
    float*    lpart = (float*)(ws + (56ull << 20) + (128ull << 10));
    _Float16* wq16  = (_Float16*)(ws + (57ull << 20));
    _Float16* wk16  = (_Float16*)(ws + (57ull << 20) + (512ull << 10));

    packcast_kernel<<<4096, 256, 0, stream>>>(Mem, vp, Wq, Wk, wq16, wk16);
    proj_kernel<<<dim3(128, 8, 2), 256, 0, stream>>>(F, wq16, bq, q16, Mem, wk16, bk, k16);
    flash_kernel<<<512, 256, 0, stream>>>(q16, k16, vp, opart, mpart, lpart);
    merge_kernel<<<16384, 256, 0, stream>>>(opart, mpart, lpart, F, out);
}